// Round 7
// baseline (383.481 us; speedup 1.0000x reference)
//
#include <hip/hip_runtime.h>
#include <math.h>

#define WID 1024
#define HEI 1024
#define OUTC 48      // output cols per wave
#define HALOC 8      // halo lanes each side (supports K<=7)
#define BH 64        // output rows per wave
#define CB 22        // col bands: 21*48 + 16 = 1024
#define RB (HEI/BH)  // 16

__device__ __forceinline__ float lane_up1(float v) {   // lane i <- lane i-1
    return __int_as_float(__builtin_amdgcn_update_dpp(
        __float_as_int(v), __float_as_int(v), 0x138, 0xF, 0xF, false)); // wave_shr:1
}
__device__ __forceinline__ float lane_dn1(float v) {   // lane i <- lane i+1
    return __int_as_float(__builtin_amdgcn_update_dpp(
        __float_as_int(v), __float_as_int(v), 0x130, 0xF, 0xF, false)); // wave_shl:1
}

// ---------------- fast body: interior waves, no image-boundary masking ----------------
template<int K, bool FIRST, bool WIMG>
__device__ __forceinline__ void fast_body(const float* __restrict__ imgp,
                                          float* __restrict__ outi,
                                          float* __restrict__ outs,
                                          int r0, int x, bool outLane)
{
    const float INF = INFINITY;
    float wu[K+1], wc[K+1], wd[K+1];   // stage j window: rows i-j-2, i-j-1, i-j
    float sk[K];
    #pragma unroll
    for (int j = 0; j <= K; ++j) { wu[j]=INF; wc[j]=INF; wd[j]=INF; }
    #pragma unroll
    for (int t = 0; t < K; ++t) sk[t] = 0.f;

    // walking offsets (elements); all rows provably in-image for interior bands
    uint32_t offLI = (uint32_t)((r0 - K)*WID + x);       // img load row at step s
    uint32_t offLS = (uint32_t)((r0 - K - 2)*WID + x);   // skel load row
    uint32_t offSI = (uint32_t)((r0 - 2*K - 1)*WID + x); // img store row
    uint32_t offSS = (uint32_t)((r0 - 2*K - 2)*WID + x); // skel store row

    float vcur = imgp[(uint32_t)((r0 - K - 1)*WID + x)];
    float scur = 0.f;

    auto step = [&](bool ldI, bool ldS, bool stI, bool stS) {
        float vnext = INF, snext = 0.f;
        if (ldI)            vnext = imgp[offLI];
        if (ldS && !FIRST)  snext = outs[offLS];
        offLI += WID; offLS += WID;

        wu[0] = wc[0]; wc[0] = wd[0]; wd[0] = vcur;
        #pragma unroll
        for (int j = 1; j <= K; ++j) {
            float ce = wc[j-1];
            float lf = lane_up1(ce), rt = lane_dn1(ce);
            float nj = fminf(fminf(fminf(fminf(wu[j-1], wd[j-1]), ce), lf), rt);
            wu[j] = wc[j]; wc[j] = wd[j]; wd[j] = nj;
        }
        #pragma unroll
        for (int t = K-1; t >= 1; --t) sk[t] = sk[t-1];
        sk[0] = FIRST ? 0.f : scur;
        #pragma unroll
        for (int t = 0; t < K; ++t) {
            float vm = fmaxf(fmaxf(wu[t+1], wd[t+1]), wc[t+1]);
            float hl = lane_up1(vm), hr = lane_dn1(vm);
            float d  = fmaxf(fmaxf(hl, hr), vm);
            float delta = fmaxf(wu[t] - d, 0.f);
            float sv = sk[t];
            sk[t] = sv + fmaxf(fmaf(-sv, delta, delta), 0.f);
        }
        if (stS && outLane)         outs[offSS] = sk[K-1];
        if (WIMG && stI && outLane) outi[offSI] = wd[K];
        offSI += WID; offSS += WID;
        vcur = vnext; scur = snext;
    };

    // fill: s in [0, 2K+2)
    #pragma unroll 1
    for (int s = 0; s < 2*K + 2; ++s)
        step(true, s >= K+2, WIMG && s == 2*K+1, false);
    // main: s in [2K+2, BH+K+2) — no conditionals
    #pragma unroll 4
    for (int m = 0; m < BH - K; ++m)
        step(true, true, true, true);
    // drain: s in [BH+K+2, BH+2K+2) — img loads still needed (deep stages), no skel loads
    #pragma unroll 1
    for (int s = BH + K + 2; s < BH + 2*K + 2; ++s)
        step(true, false, s < BH + 2*K + 1, true);
}

// ---------------- masked body: boundary waves (round-6 general loop) ----------------
template<int K, bool FIRST, bool WIMG>
__device__ __forceinline__ void masked_body(const float* __restrict__ imgp,
                                            float* __restrict__ outi,
                                            float* __restrict__ outs,
                                            int r0, int x, bool colIn, bool outLane)
{
    const float INF = INFINITY;
    float wu[K+1], wc[K+1], wd[K+1], sk[K];
    #pragma unroll
    for (int j = 0; j <= K; ++j) { wu[j]=INF; wc[j]=INF; wd[j]=INF; }
    #pragma unroll
    for (int t = 0; t < K; ++t) sk[t] = 0.f;

    const int i0 = r0 - K - 1;
    const int isteps = BH + 2*K + 2;

    float vcur = (colIn && (unsigned)i0 < (unsigned)HEI) ? imgp[(size_t)i0*WID + x] : INF;
    float scur = 0.f;
    if (!FIRST) {
        int sr = i0 - 2;
        if (colIn && sr >= r0 && sr < r0+BH) scur = outs[(size_t)sr*WID + x];
    }

    #pragma unroll 1
    for (int s = 0; s < isteps; ++s) {
        const int i = i0 + s;
        float vnext, snext = 0.f;
        {
            int rn = i + 1;
            vnext = (colIn && (unsigned)rn < (unsigned)HEI) ? imgp[(size_t)rn*WID + x] : INF;
        }
        if (!FIRST) {
            int sr = i - 1;
            if (colIn && sr >= r0 && sr < r0+BH) snext = outs[(size_t)sr*WID + x];
        }

        wu[0] = wc[0]; wc[0] = wd[0]; wd[0] = vcur;
        #pragma unroll
        for (int j = 1; j <= K; ++j) {
            float ce = wc[j-1];
            float lf = lane_up1(ce), rt = lane_dn1(ce);
            float nj = fminf(fminf(fminf(fminf(wu[j-1], wd[j-1]), ce), lf), rt);
            int rj = i - j;
            nj = ((unsigned)rj < (unsigned)HEI) ? nj : INF;
            nj = colIn ? nj : INF;
            wu[j] = wc[j]; wc[j] = wd[j]; wd[j] = nj;
        }
        #pragma unroll
        for (int t = K-1; t >= 1; --t) sk[t] = sk[t-1];
        sk[0] = FIRST ? 0.f : scur;
        #pragma unroll
        for (int t = 0; t < K; ++t) {
            int ro = i - 2 - t;
            float um = (ro >= 1)     ? wu[t+1] : -INF;
            float dm = (ro <= HEI-2) ? wd[t+1] : -INF;
            float vm = fmaxf(fmaxf(um, dm), wc[t+1]);
            vm = colIn ? vm : -INF;
            float hl = lane_up1(vm), hr = lane_dn1(vm);
            float d  = fmaxf(fmaxf(hl, hr), vm);
            float delta = fmaxf(wu[t] - d, 0.f);
            float sv = sk[t];
            sk[t] = sv + fmaxf(fmaf(-sv, delta, delta), 0.f);
        }
        {
            int rs = i - K - 1;
            if (rs >= r0 && rs < r0+BH && outLane) outs[(size_t)rs*WID + x] = sk[K-1];
        }
        if (WIMG) {
            int re = i - K;
            if (re >= r0 && re < r0+BH && outLane) outi[(size_t)re*WID + x] = wd[K];
        }
        vcur = vnext; scur = snext;
    }
}

template<int K, bool FIRST, bool WIMG>
__global__ __launch_bounds__(256)
void pass_kernel(const float* __restrict__ img_in, float* __restrict__ img_out,
                 float* __restrict__ skel, int nwaves)
{
    const int lane = threadIdx.x & 63;
    const int wid  = blockIdx.x*4 + (threadIdx.x >> 6);
    if (wid >= nwaves) return;
    const int perImg = CB*RB;
    const int b   = wid / perImg;
    const int rem = wid - b*perImg;
    const int cb  = rem % CB;
    const int rb  = rem / CB;
    const int outc = (WID - cb*OUTC < OUTC) ? (WID - cb*OUTC) : OUTC;
    const int x0  = cb*OUTC - HALOC;
    const int r0  = rb*BH;
    const int x   = x0 + lane;
    const bool colIn   = ((unsigned)x < (unsigned)WID);
    const bool outLane = (lane >= HALOC) && (lane < HALOC + outc);
    const size_t base = (size_t)b*HEI*WID;

    const float* imgp = img_in + base;
    float* outi = WIMG ? (img_out + base) : nullptr;
    float* outs = skel + base;

    const bool fast = (cb >= 1) && (cb <= CB-2) && (rb >= 1) && (rb <= RB-2);
    if (fast)
        fast_body<K, FIRST, WIMG>(imgp, outi, outs, r0, x, outLane);
    else
        masked_body<K, FIRST, WIMG>(imgp, outi, outs, r0, x, colIn, outLane);
}

extern "C" void kernel_launch(void* const* d_in, const int* in_sizes, int n_in,
                              void* d_out, int out_size, void* d_ws, size_t ws_size,
                              hipStream_t stream)
{
    const float* img = (const float*)d_in[0];
    float* skel = (float*)d_out;
    const int total = in_sizes[0];
    const int B = total / (HEI*WID);

    float* bufA = (float*)d_ws;
    float* bufB = bufA + (size_t)total;

    const int nw = B * CB * RB;
    const int blocks = (nw + 3) / 4;

    // 41 ops (t=0..40): 5 passes of K=7, then K=6.
    pass_kernel<7,true, true ><<<blocks,256,0,stream>>>(img,  bufA, skel, nw); // t=0..6
    pass_kernel<7,false,true ><<<blocks,256,0,stream>>>(bufA, bufB, skel, nw); // t=7..13
    pass_kernel<7,false,true ><<<blocks,256,0,stream>>>(bufB, bufA, skel, nw); // t=14..20
    pass_kernel<7,false,true ><<<blocks,256,0,stream>>>(bufA, bufB, skel, nw); // t=21..27
    pass_kernel<7,false,true ><<<blocks,256,0,stream>>>(bufB, bufA, skel, nw); // t=28..34
    pass_kernel<6,false,false><<<blocks,256,0,stream>>>(bufA, nullptr, skel, nw); // t=35..40
}

// Round 8
// 306.499 us; speedup vs baseline: 1.2512x; 1.2512x over previous
//
#include <hip/hip_runtime.h>
#include <math.h>

#define WID 1024
#define HEI 1024
#define OUTC 48      // output cols per wave
#define HALOC 8      // halo lanes each side (supports K<=7)
#define BH 32        // output rows per wave
#define CB 22        // col bands: 21*48 + 16 = 1024
#define RB (HEI/BH)  // 32

__device__ __forceinline__ float lane_up1(float v) {   // lane i <- lane i-1
    return __int_as_float(__builtin_amdgcn_update_dpp(
        __float_as_int(v), __float_as_int(v), 0x138, 0xF, 0xF, false)); // wave_shr:1
}
__device__ __forceinline__ float lane_dn1(float v) {   // lane i <- lane i+1
    return __int_as_float(__builtin_amdgcn_update_dpp(
        __float_as_int(v), __float_as_int(v), 0x130, 0xF, 0xF, false)); // wave_shl:1
}

// ---------------- fast body: interior waves, no image-boundary masking ----------------
template<int K, bool FIRST, bool WIMG>
__device__ __forceinline__ void fast_body(const float* __restrict__ imgp,
                                          float* __restrict__ outi,
                                          float* __restrict__ outs,
                                          int r0, int x, bool outLane)
{
    const float INF = INFINITY;
    float wu[K+1], wc[K+1], wd[K+1];   // stage j window: rows i-j-2, i-j-1, i-j
    float sk[K];
    #pragma unroll
    for (int j = 0; j <= K; ++j) { wu[j]=INF; wc[j]=INF; wd[j]=INF; }
    #pragma unroll
    for (int t = 0; t < K; ++t) sk[t] = 0.f;

    // walking element offsets; all touched rows provably in-image for interior waves
    uint32_t offLI = (uint32_t)((r0 - K)*WID + x);       // img load row
    uint32_t offLS = (uint32_t)((r0 - K - 2)*WID + x);   // skel load row
    uint32_t offSI = (uint32_t)((r0 - 2*K - 1)*WID + x); // img store row
    uint32_t offSS = (uint32_t)((r0 - 2*K - 2)*WID + x); // skel store row

    float vcur = imgp[(uint32_t)((r0 - K - 1)*WID + x)];
    float scur = 0.f;

    auto step = [&](bool ldI, bool ldS, bool stI, bool stS) {
        float vnext = INF, snext = 0.f;
        if (ldI)            vnext = imgp[offLI];
        if (ldS && !FIRST)  snext = outs[offLS];
        offLI += WID; offLS += WID;

        wu[0] = wc[0]; wc[0] = wd[0]; wd[0] = vcur;
        #pragma unroll
        for (int j = 1; j <= K; ++j) {
            float ce = wc[j-1];
            float lf = lane_up1(ce), rt = lane_dn1(ce);
            float nj = fminf(fminf(fminf(fminf(wu[j-1], wd[j-1]), ce), lf), rt);
            wu[j] = wc[j]; wc[j] = wd[j]; wd[j] = nj;
        }
        #pragma unroll
        for (int t = K-1; t >= 1; --t) sk[t] = sk[t-1];
        sk[0] = FIRST ? 0.f : scur;
        #pragma unroll
        for (int t = 0; t < K; ++t) {
            float vm = fmaxf(fmaxf(wu[t+1], wd[t+1]), wc[t+1]);
            float hl = lane_up1(vm), hr = lane_dn1(vm);
            float d  = fmaxf(fmaxf(hl, hr), vm);
            float delta = fmaxf(wu[t] - d, 0.f);
            float sv = sk[t];
            sk[t] = sv + fmaxf(fmaf(-sv, delta, delta), 0.f);
        }
        if (stS && outLane)         outs[offSS] = sk[K-1];
        if (WIMG && stI && outLane) outi[offSI] = wd[K];
        offSI += WID; offSS += WID;
        vcur = vnext; scur = snext;
    };

    // fill segment 1: s in [0, K+2) — img loads only
    #pragma unroll 1
    for (int s = 0; s < K + 2; ++s)
        step(true, false, false, false);
    // fill segment 2: s in [K+2, 2K+1) — img + skel loads
    #pragma unroll 1
    for (int s = K + 2; s < 2*K + 1; ++s)
        step(true, true, false, false);
    // last fill step s = 2K+1: first img store
    step(true, true, WIMG, false);
    // main: BH-K steps, no conditionals, unrolled for register renaming
    #pragma unroll 5
    for (int m = 0; m < BH - K; ++m)
        step(true, true, true, true);
    // drain: K steps; no skel loads; img stores for first K-1
    #pragma unroll 1
    for (int s = 0; s < K - 1; ++s)
        step(true, false, true, true);
    step(true, false, false, true);
}

// ---------------- masked body: boundary waves ----------------
template<int K, bool FIRST, bool WIMG>
__device__ __forceinline__ void masked_body(const float* __restrict__ imgp,
                                            float* __restrict__ outi,
                                            float* __restrict__ outs,
                                            int r0, int x, bool colIn, bool outLane)
{
    const float INF = INFINITY;
    float wu[K+1], wc[K+1], wd[K+1], sk[K];
    #pragma unroll
    for (int j = 0; j <= K; ++j) { wu[j]=INF; wc[j]=INF; wd[j]=INF; }
    #pragma unroll
    for (int t = 0; t < K; ++t) sk[t] = 0.f;

    const int i0 = r0 - K - 1;
    const int isteps = BH + 2*K + 2;

    float vcur = (colIn && (unsigned)i0 < (unsigned)HEI) ? imgp[(size_t)i0*WID + x] : INF;
    float scur = 0.f;
    if (!FIRST) {
        int sr = i0 - 2;
        if (colIn && sr >= r0 && sr < r0+BH) scur = outs[(size_t)sr*WID + x];
    }

    #pragma unroll 1
    for (int s = 0; s < isteps; ++s) {
        const int i = i0 + s;
        float vnext, snext = 0.f;
        {
            int rn = i + 1;
            vnext = (colIn && (unsigned)rn < (unsigned)HEI) ? imgp[(size_t)rn*WID + x] : INF;
        }
        if (!FIRST) {
            int sr = i - 1;
            if (colIn && sr >= r0 && sr < r0+BH) snext = outs[(size_t)sr*WID + x];
        }

        wu[0] = wc[0]; wc[0] = wd[0]; wd[0] = vcur;
        #pragma unroll
        for (int j = 1; j <= K; ++j) {
            float ce = wc[j-1];
            float lf = lane_up1(ce), rt = lane_dn1(ce);
            float nj = fminf(fminf(fminf(fminf(wu[j-1], wd[j-1]), ce), lf), rt);
            int rj = i - j;
            nj = ((unsigned)rj < (unsigned)HEI) ? nj : INF;
            nj = colIn ? nj : INF;
            wu[j] = wc[j]; wc[j] = wd[j]; wd[j] = nj;
        }
        #pragma unroll
        for (int t = K-1; t >= 1; --t) sk[t] = sk[t-1];
        sk[0] = FIRST ? 0.f : scur;
        #pragma unroll
        for (int t = 0; t < K; ++t) {
            int ro = i - 2 - t;
            float um = (ro >= 1)     ? wu[t+1] : -INF;
            float dm = (ro <= HEI-2) ? wd[t+1] : -INF;
            float vm = fmaxf(fmaxf(um, dm), wc[t+1]);
            vm = colIn ? vm : -INF;
            float hl = lane_up1(vm), hr = lane_dn1(vm);
            float d  = fmaxf(fmaxf(hl, hr), vm);
            float delta = fmaxf(wu[t] - d, 0.f);
            float sv = sk[t];
            sk[t] = sv + fmaxf(fmaf(-sv, delta, delta), 0.f);
        }
        {
            int rs = i - K - 1;
            if (rs >= r0 && rs < r0+BH && outLane) outs[(size_t)rs*WID + x] = sk[K-1];
        }
        if (WIMG) {
            int re = i - K;
            if (re >= r0 && re < r0+BH && outLane) outi[(size_t)re*WID + x] = wd[K];
        }
        vcur = vnext; scur = snext;
    }
}

template<int K, bool FIRST, bool WIMG>
__global__ __launch_bounds__(256)
void pass_kernel(const float* __restrict__ img_in, float* __restrict__ img_out,
                 float* __restrict__ skel, int nwaves)
{
    const int lane = threadIdx.x & 63;
    const int wid  = blockIdx.x*4 + (threadIdx.x >> 6);
    if (wid >= nwaves) return;
    const int perImg = CB*RB;
    const int b   = wid / perImg;
    const int rem = wid - b*perImg;
    const int cb  = rem % CB;
    const int rb  = rem / CB;
    const int outc = (WID - cb*OUTC < OUTC) ? (WID - cb*OUTC) : OUTC;
    const int x0  = cb*OUTC - HALOC;
    const int r0  = rb*BH;
    const int x   = x0 + lane;
    const bool colIn   = ((unsigned)x < (unsigned)WID);
    const bool outLane = (lane >= HALOC) && (lane < HALOC + outc);
    const size_t base = (size_t)b*HEI*WID;

    const float* imgp = img_in + base;
    float* outi = WIMG ? (img_out + base) : nullptr;
    float* outs = skel + base;

    const bool fast = (cb >= 1) && (cb <= CB-2) && (rb >= 1) && (rb <= RB-2);
    if (fast)
        fast_body<K, FIRST, WIMG>(imgp, outi, outs, r0, x, outLane);
    else
        masked_body<K, FIRST, WIMG>(imgp, outi, outs, r0, x, colIn, outLane);
}

extern "C" void kernel_launch(void* const* d_in, const int* in_sizes, int n_in,
                              void* d_out, int out_size, void* d_ws, size_t ws_size,
                              hipStream_t stream)
{
    const float* img = (const float*)d_in[0];
    float* skel = (float*)d_out;
    const int total = in_sizes[0];
    const int B = total / (HEI*WID);

    float* bufA = (float*)d_ws;
    float* bufB = bufA + (size_t)total;

    const int nw = B * CB * RB;
    const int blocks = (nw + 3) / 4;

    // 41 ops (t=0..40): 5 passes of K=7, then K=6.
    pass_kernel<7,true, true ><<<blocks,256,0,stream>>>(img,  bufA, skel, nw); // t=0..6
    pass_kernel<7,false,true ><<<blocks,256,0,stream>>>(bufA, bufB, skel, nw); // t=7..13
    pass_kernel<7,false,true ><<<blocks,256,0,stream>>>(bufB, bufA, skel, nw); // t=14..20
    pass_kernel<7,false,true ><<<blocks,256,0,stream>>>(bufA, bufB, skel, nw); // t=21..27
    pass_kernel<7,false,true ><<<blocks,256,0,stream>>>(bufB, bufA, skel, nw); // t=28..34
    pass_kernel<6,false,false><<<blocks,256,0,stream>>>(bufA, nullptr, skel, nw); // t=35..40
}

// Round 9
// 298.583 us; speedup vs baseline: 1.2843x; 1.0265x over previous
//
#include <hip/hip_runtime.h>
#include <math.h>

#define WID 1024
#define HEI 1024
#define OUTC 48      // output cols per wave
#define HALOC 8      // halo lanes each side (supports K<=7)
#define BH 32        // output rows per wave
#define CB 22        // col bands: 21*48 + 16 = 1024
#define RB (HEI/BH)  // 32

__device__ __forceinline__ float lane_up1(float v) {   // lane i <- lane i-1
    return __int_as_float(__builtin_amdgcn_update_dpp(
        __float_as_int(v), __float_as_int(v), 0x138, 0xF, 0xF, false)); // wave_shr:1
}
__device__ __forceinline__ float lane_dn1(float v) {   // lane i <- lane i+1
    return __int_as_float(__builtin_amdgcn_update_dpp(
        __float_as_int(v), __float_as_int(v), 0x130, 0xF, 0xF, false)); // wave_shl:1
}
__device__ __forceinline__ float fmin3(float a, float b, float c) {
    float d; asm("v_min3_f32 %0, %1, %2, %3" : "=v"(d) : "v"(a), "v"(b), "v"(c));
    return d;
}
__device__ __forceinline__ float fmax3(float a, float b, float c) {
    float d; asm("v_max3_f32 %0, %1, %2, %3" : "=v"(d) : "v"(a), "v"(b), "v"(c));
    return d;
}

// ---------------- fast body: interior waves, no image-boundary masking ----------------
template<int K, bool FIRST, bool WIMG>
__device__ __forceinline__ void fast_body(const float* __restrict__ imgp,
                                          float* __restrict__ outi,
                                          float* __restrict__ outs,
                                          int r0, int x, bool outLane)
{
    const float INF = INFINITY;
    float wu[K+1], wc[K+1], wd[K+1];   // stage j window: rows i-j-2, i-j-1, i-j
    float sk[K];
    #pragma unroll
    for (int j = 0; j <= K; ++j) { wu[j]=INF; wc[j]=INF; wd[j]=INF; }
    #pragma unroll
    for (int t = 0; t < K; ++t) sk[t] = 0.f;

    uint32_t offLI = (uint32_t)((r0 - K)*WID + x);       // img load row
    uint32_t offLS = (uint32_t)((r0 - K - 2)*WID + x);   // skel load row
    uint32_t offSI = (uint32_t)((r0 - 2*K - 1)*WID + x); // img store row
    uint32_t offSS = (uint32_t)((r0 - 2*K - 2)*WID + x); // skel store row

    float vcur = imgp[(uint32_t)((r0 - K - 1)*WID + x)];
    float scur = 0.f;

    auto step = [&](bool ldI, bool ldS, bool stI, bool stS, bool doOps) {
        float vnext = INF, snext = 0.f;
        if (ldI)            vnext = imgp[offLI];
        if (ldS && !FIRST)  snext = outs[offLS];
        offLI += WID; offLS += WID;

        wu[0] = wc[0]; wc[0] = wd[0]; wd[0] = vcur;
        #pragma unroll
        for (int j = 1; j <= K; ++j) {
            float ce = wc[j-1];                       // prev-step value: ready early
            float lf = lane_up1(ce), rt = lane_dn1(ce);
            float pre = fmin3(wu[j-1], ce, lf);       // early operands first
            float nj  = fmin3(pre, rt, wd[j-1]);      // serial-chain input enters last
            wu[j] = wc[j]; wc[j] = wd[j]; wd[j] = nj;
        }
        #pragma unroll
        for (int t = K-1; t >= 1; --t) sk[t] = sk[t-1];
        sk[0] = FIRST ? 0.f : scur;
        if (doOps) {
            #pragma unroll
            for (int t = 0; t < K; ++t) {
                float vm = fmax3(wu[t+1], wc[t+1], wd[t+1]);
                float hl = lane_up1(vm), hr = lane_dn1(vm);
                float d  = fmax3(hl, hr, vm);
                float delta = fmaxf(wu[t] - d, 0.f);
                float sv = sk[t];
                sk[t] = sv + fmaxf(fmaf(-sv, delta, delta), 0.f);
            }
        }
        if (stS && outLane)         outs[offSS] = sk[K-1];
        if (WIMG && stI && outLane) outi[offSI] = wd[K];
        offSI += WID; offSS += WID;
        vcur = vnext; scur = snext;
    };

    // fill1: s in [0, K+2) — erode chain priming only
    #pragma unroll 1
    for (int s = 0; s < K + 2; ++s)
        step(true, false, false, false, false);
    // fill2: s in [K+2, 2K+1) — skel entries in flight
    #pragma unroll 1
    for (int s = K + 2; s < 2*K + 1; ++s)
        step(true, true, false, false, true);
    // fill3: first img store
    step(true, true, WIMG, false, true);
    // main: BH-K steps, fully unrolled -> static ring indices, zero movs
    #pragma unroll
    for (int m = 0; m < BH - K; ++m)
        step(true, true, true, true, true);
    // drain
    #pragma unroll 1
    for (int s = 0; s < K - 1; ++s)
        step(true, false, true, true, true);
    step(true, false, false, true, true);
}

// ---------------- masked body: boundary waves ----------------
template<int K, bool FIRST, bool WIMG>
__device__ __forceinline__ void masked_body(const float* __restrict__ imgp,
                                            float* __restrict__ outi,
                                            float* __restrict__ outs,
                                            int r0, int x, bool colIn, bool outLane)
{
    const float INF = INFINITY;
    float wu[K+1], wc[K+1], wd[K+1], sk[K];
    #pragma unroll
    for (int j = 0; j <= K; ++j) { wu[j]=INF; wc[j]=INF; wd[j]=INF; }
    #pragma unroll
    for (int t = 0; t < K; ++t) sk[t] = 0.f;

    const int i0 = r0 - K - 1;
    const int isteps = BH + 2*K + 2;

    float vcur = (colIn && (unsigned)i0 < (unsigned)HEI) ? imgp[(size_t)i0*WID + x] : INF;
    float scur = 0.f;
    if (!FIRST) {
        int sr = i0 - 2;
        if (colIn && sr >= r0 && sr < r0+BH) scur = outs[(size_t)sr*WID + x];
    }

    #pragma unroll 1
    for (int s = 0; s < isteps; ++s) {
        const int i = i0 + s;
        float vnext, snext = 0.f;
        {
            int rn = i + 1;
            vnext = (colIn && (unsigned)rn < (unsigned)HEI) ? imgp[(size_t)rn*WID + x] : INF;
        }
        if (!FIRST) {
            int sr = i - 1;
            if (colIn && sr >= r0 && sr < r0+BH) snext = outs[(size_t)sr*WID + x];
        }

        wu[0] = wc[0]; wc[0] = wd[0]; wd[0] = vcur;
        #pragma unroll
        for (int j = 1; j <= K; ++j) {
            float ce = wc[j-1];
            float lf = lane_up1(ce), rt = lane_dn1(ce);
            float pre = fmin3(wu[j-1], ce, lf);
            float nj  = fmin3(pre, rt, wd[j-1]);
            int rj = i - j;
            nj = ((unsigned)rj < (unsigned)HEI) ? nj : INF;
            nj = colIn ? nj : INF;
            wu[j] = wc[j]; wc[j] = wd[j]; wd[j] = nj;
        }
        #pragma unroll
        for (int t = K-1; t >= 1; --t) sk[t] = sk[t-1];
        sk[0] = FIRST ? 0.f : scur;
        #pragma unroll
        for (int t = 0; t < K; ++t) {
            int ro = i - 2 - t;
            float um = (ro >= 1)     ? wu[t+1] : -INF;
            float dm = (ro <= HEI-2) ? wd[t+1] : -INF;
            float vm = fmax3(um, dm, wc[t+1]);
            vm = colIn ? vm : -INF;
            float hl = lane_up1(vm), hr = lane_dn1(vm);
            float d  = fmax3(hl, hr, vm);
            float delta = fmaxf(wu[t] - d, 0.f);
            float sv = sk[t];
            sk[t] = sv + fmaxf(fmaf(-sv, delta, delta), 0.f);
        }
        {
            int rs = i - K - 1;
            if (rs >= r0 && rs < r0+BH && outLane) outs[(size_t)rs*WID + x] = sk[K-1];
        }
        if (WIMG) {
            int re = i - K;
            if (re >= r0 && re < r0+BH && outLane) outi[(size_t)re*WID + x] = wd[K];
        }
        vcur = vnext; scur = snext;
    }
}

template<int K, bool FIRST, bool WIMG>
__global__ __launch_bounds__(256, 4)
void pass_kernel(const float* __restrict__ img_in, float* __restrict__ img_out,
                 float* __restrict__ skel, int nwaves)
{
    const int lane = threadIdx.x & 63;
    const int wid  = blockIdx.x*4 + (threadIdx.x >> 6);
    if (wid >= nwaves) return;
    const int perImg = CB*RB;
    const int b   = wid / perImg;
    const int rem = wid - b*perImg;
    const int cb  = rem % CB;
    const int rb  = rem / CB;
    const int outc = (WID - cb*OUTC < OUTC) ? (WID - cb*OUTC) : OUTC;
    const int x0  = cb*OUTC - HALOC;
    const int r0  = rb*BH;
    const int x   = x0 + lane;
    const bool colIn   = ((unsigned)x < (unsigned)WID);
    const bool outLane = (lane >= HALOC) && (lane < HALOC + outc);
    const size_t base = (size_t)b*HEI*WID;

    const float* imgp = img_in + base;
    float* outi = WIMG ? (img_out + base) : nullptr;
    float* outs = skel + base;

    const bool fast = (cb >= 1) && (cb <= CB-2) && (rb >= 1) && (rb <= RB-2);
    if (fast)
        fast_body<K, FIRST, WIMG>(imgp, outi, outs, r0, x, outLane);
    else
        masked_body<K, FIRST, WIMG>(imgp, outi, outs, r0, x, colIn, outLane);
}

extern "C" void kernel_launch(void* const* d_in, const int* in_sizes, int n_in,
                              void* d_out, int out_size, void* d_ws, size_t ws_size,
                              hipStream_t stream)
{
    const float* img = (const float*)d_in[0];
    float* skel = (float*)d_out;
    const int total = in_sizes[0];
    const int B = total / (HEI*WID);

    float* bufA = (float*)d_ws;
    float* bufB = bufA + (size_t)total;

    const int nw = B * CB * RB;
    const int blocks = (nw + 3) / 4;

    // 41 ops (t=0..40): 5 passes of K=7, then K=6.
    pass_kernel<7,true, true ><<<blocks,256,0,stream>>>(img,  bufA, skel, nw); // t=0..6
    pass_kernel<7,false,true ><<<blocks,256,0,stream>>>(bufA, bufB, skel, nw); // t=7..13
    pass_kernel<7,false,true ><<<blocks,256,0,stream>>>(bufB, bufA, skel, nw); // t=14..20
    pass_kernel<7,false,true ><<<blocks,256,0,stream>>>(bufA, bufB, skel, nw); // t=21..27
    pass_kernel<7,false,true ><<<blocks,256,0,stream>>>(bufB, bufA, skel, nw); // t=28..34
    pass_kernel<6,false,false><<<blocks,256,0,stream>>>(bufA, nullptr, skel, nw); // t=35..40
}

// Round 10
// 264.655 us; speedup vs baseline: 1.4490x; 1.1282x over previous
//
#include <hip/hip_runtime.h>
#include <math.h>

#define WID 1024
#define HEI 1024
#define OUTC 48      // output cols per wave
#define HALOC 8      // halo lanes each side (supports K<=7)
#define BH 32        // output rows per wave
#define CB 22        // col bands: 21*48 + 16 = 1024
#define RB 32        // row bands = 8 rbg * 4 warps

__device__ __forceinline__ float lane_up1(float v) {   // lane i <- lane i-1
    return __int_as_float(__builtin_amdgcn_update_dpp(
        __float_as_int(v), __float_as_int(v), 0x138, 0xF, 0xF, false)); // wave_shr:1
}
__device__ __forceinline__ float lane_dn1(float v) {   // lane i <- lane i+1
    return __int_as_float(__builtin_amdgcn_update_dpp(
        __float_as_int(v), __float_as_int(v), 0x130, 0xF, 0xF, false)); // wave_shl:1
}
__device__ __forceinline__ float fmin3(float a, float b, float c) {
    float d; asm("v_min3_f32 %0, %1, %2, %3" : "=v"(d) : "v"(a), "v"(b), "v"(c));
    return d;
}
__device__ __forceinline__ float fmax3(float a, float b, float c) {
    float d; asm("v_max3_f32 %0, %1, %2, %3" : "=v"(d) : "v"(a), "v"(b), "v"(c));
    return d;
}

// ---------------- fast body: interior waves, fully static 48-step sweep ----------------
template<int K, bool FIRST, bool WIMG>
__device__ __forceinline__ void fast_body(const float* __restrict__ imgp,
                                          float* __restrict__ outi,
                                          float* __restrict__ outs,
                                          int r0, int x, bool outLane)
{
    constexpr int NS = BH + 2*K + 2;
    const float INF = INFINITY;
    float wu[K+1], wc[K+1], wd[K+1], sk[K];
    #pragma unroll
    for (int j = 0; j <= K; ++j) { wu[j]=INF; wc[j]=INF; wd[j]=INF; }
    #pragma unroll
    for (int t = 0; t < K; ++t) sk[t] = 0.f;

    const int i0 = r0 - K - 1;
    const float* pI  = imgp + (size_t)(i0+2)*WID + x;  // img row loaded at step s: i0+2+s
    const float* pS  = outs + (size_t)(r0+2)*WID + x;  // skel row loaded at step s: r0+2+(s-(K+3))
    float*       pSS = outs + (size_t)r0*WID + x;      // skel stores: rows r0.. from s=2K+2
    float*       pSI = outi + (size_t)r0*WID + x;      // img stores:  rows r0.. from s=2K+1

    // depth-2 prefetch rings (parity on consuming step)
    float vb0 = imgp[(size_t)i0*WID + x];              // consumed at s=0
    float vb1 = imgp[(size_t)(i0+1)*WID + x];          // consumed at s=1
    float sb0 = 0.f, sb1 = 0.f;
    if (!FIRST) {
        float s0 = outs[(size_t)r0*WID + x];           // consumed at s=K+3
        float s1 = outs[(size_t)(r0+1)*WID + x];       // consumed at s=K+4
        if ((K+3)&1) { sb1 = s0; sb0 = s1; } else { sb0 = s0; sb1 = s1; }
    }

    #pragma unroll
    for (int s = 0; s < NS; ++s) {
        float vcur = (s&1) ? vb1 : vb0;
        if (s+2 <= NS-1) {                     // prefetch img row for step s+2
            float v = pI[0]; pI += WID;
            if (s&1) vb1 = v; else vb0 = v;
        }
        float scur = (s&1) ? sb1 : sb0;
        if (!FIRST && (s+2 >= K+5) && (s+2 <= BH+K+2)) {  // prefetch skel row for s+2
            float v = pS[0]; pS += WID;
            if (s&1) sb1 = v; else sb0 = v;
        }

        // stage 0 (img) shift
        wu[0] = wc[0]; wc[0] = wd[0]; wd[0] = vcur;

        // erode stages, triangle: stage j active from s = 2j
        #pragma unroll
        for (int j = 1; j <= K; ++j) {
            if (s >= 2*j) {
                float ce = wc[j-1];
                float lf = lane_up1(ce), rt = lane_dn1(ce);
                float pre = fmin3(wu[j-1], ce, lf);
                float nj  = fmin3(pre, rt, wd[j-1]);
                wu[j] = wc[j]; wc[j] = wd[j]; wd[j] = nj;
            }
        }

        // skel ring shift; fresh row i-2 enters
        #pragma unroll
        for (int t = K-1; t >= 1; --t) sk[t] = sk[t-1];
        sk[0] = FIRST ? 0.f : scur;

        // dilate+update ops, triangle: op t active s in [K+3+t, K+2+BH+t]
        #pragma unroll
        for (int t = 0; t < K; ++t) {
            if (s >= K+3+t && s <= K+2+BH+t) {
                float vm = fmax3(wu[t+1], wc[t+1], wd[t+1]);
                float hl = lane_up1(vm), hr = lane_dn1(vm);
                float d  = fmax3(hl, hr, vm);
                float delta = fmaxf(wu[t] - d, 0.f);
                float sv = sk[t];
                sk[t] = sv + fmaf(-sv, delta, delta);   // delta*(1-sv) >= 0, relu is no-op
            }
        }

        if (s >= 2*K+2) { if (outLane) pSS[0] = sk[K-1]; pSS += WID; }
        if (WIMG) {
            if (s >= 2*K+1 && s <= BH+2*K) { if (outLane) pSI[0] = wd[K]; pSI += WID; }
        }
    }
}

// ---------------- masked body: boundary waves ----------------
template<int K, bool FIRST, bool WIMG>
__device__ __forceinline__ void masked_body(const float* __restrict__ imgp,
                                            float* __restrict__ outi,
                                            float* __restrict__ outs,
                                            int r0, int x, bool colIn, bool outLane)
{
    const float INF = INFINITY;
    float wu[K+1], wc[K+1], wd[K+1], sk[K];
    #pragma unroll
    for (int j = 0; j <= K; ++j) { wu[j]=INF; wc[j]=INF; wd[j]=INF; }
    #pragma unroll
    for (int t = 0; t < K; ++t) sk[t] = 0.f;

    const int i0 = r0 - K - 1;
    const int isteps = BH + 2*K + 2;

    float vcur = (colIn && (unsigned)i0 < (unsigned)HEI) ? imgp[(size_t)i0*WID + x] : INF;
    float scur = 0.f;
    if (!FIRST) {
        int sr = i0 - 2;
        if (colIn && sr >= r0 && sr < r0+BH) scur = outs[(size_t)sr*WID + x];
    }

    #pragma unroll 1
    for (int s = 0; s < isteps; ++s) {
        const int i = i0 + s;
        float vnext, snext = 0.f;
        {
            int rn = i + 1;
            vnext = (colIn && (unsigned)rn < (unsigned)HEI) ? imgp[(size_t)rn*WID + x] : INF;
        }
        if (!FIRST) {
            int sr = i - 1;
            if (colIn && sr >= r0 && sr < r0+BH) snext = outs[(size_t)sr*WID + x];
        }

        wu[0] = wc[0]; wc[0] = wd[0]; wd[0] = vcur;
        #pragma unroll
        for (int j = 1; j <= K; ++j) {
            float ce = wc[j-1];
            float lf = lane_up1(ce), rt = lane_dn1(ce);
            float pre = fmin3(wu[j-1], ce, lf);
            float nj  = fmin3(pre, rt, wd[j-1]);
            int rj = i - j;
            nj = ((unsigned)rj < (unsigned)HEI) ? nj : INF;
            nj = colIn ? nj : INF;
            wu[j] = wc[j]; wc[j] = wd[j]; wd[j] = nj;
        }
        #pragma unroll
        for (int t = K-1; t >= 1; --t) sk[t] = sk[t-1];
        sk[0] = FIRST ? 0.f : scur;
        #pragma unroll
        for (int t = 0; t < K; ++t) {
            int ro = i - 2 - t;
            float um = (ro >= 1)     ? wu[t+1] : -INF;
            float dm = (ro <= HEI-2) ? wd[t+1] : -INF;
            float vm = fmax3(um, dm, wc[t+1]);
            vm = colIn ? vm : -INF;
            float hl = lane_up1(vm), hr = lane_dn1(vm);
            float d  = fmax3(hl, hr, vm);
            float delta = fmaxf(wu[t] - d, 0.f);
            float sv = sk[t];
            sk[t] = sv + fmaf(-sv, delta, delta);
        }
        {
            int rs = i - K - 1;
            if (rs >= r0 && rs < r0+BH && outLane) outs[(size_t)rs*WID + x] = sk[K-1];
        }
        if (WIMG) {
            int re = i - K;
            if (re >= r0 && re < r0+BH && outLane) outi[(size_t)re*WID + x] = wd[K];
        }
        vcur = vnext; scur = snext;
    }
}

template<int K, bool FIRST, bool WIMG>
__global__ __launch_bounds__(256, 4)
void pass_kernel(const float* __restrict__ img_in, float* __restrict__ img_out,
                 float* __restrict__ skel)
{
    const int lane = threadIdx.x & 63;
    const int warp = threadIdx.x >> 6;
    // XCD-locality swizzle: rbg = blockIdx & 7 -> XCD id (round-robin dispatch);
    // each XCD owns a contiguous 128-row stripe (4 row-bands) across all passes.
    const int bid  = blockIdx.x;
    const int rbg  = bid & 7;
    const int rest = bid >> 3;
    const int cb   = rest % CB;
    const int b    = rest / CB;
    const int rb   = rbg*4 + warp;

    const int outc = (cb == CB-1) ? (WID - (CB-1)*OUTC) : OUTC;  // 48 or 16
    const int x0   = cb*OUTC - HALOC;
    const int r0   = rb*BH;
    const int x    = x0 + lane;
    const bool colIn   = ((unsigned)x < (unsigned)WID);
    const bool outLane = (lane >= HALOC) && (lane < HALOC + outc);
    const size_t base = (size_t)b*HEI*WID;

    const float* imgp = img_in + base;
    float* outi = WIMG ? (img_out + base) : nullptr;
    float* outs = skel + base;

    const bool fast = (cb >= 1) && (cb <= CB-2) && (rb >= 1) && (rb <= RB-2);
    if (fast)
        fast_body<K, FIRST, WIMG>(imgp, outi, outs, r0, x, outLane);
    else
        masked_body<K, FIRST, WIMG>(imgp, outi, outs, r0, x, colIn, outLane);
}

extern "C" void kernel_launch(void* const* d_in, const int* in_sizes, int n_in,
                              void* d_out, int out_size, void* d_ws, size_t ws_size,
                              hipStream_t stream)
{
    const float* img = (const float*)d_in[0];
    float* skel = (float*)d_out;
    const int total = in_sizes[0];
    const int B = total / (HEI*WID);

    float* bufA = (float*)d_ws;
    float* bufB = bufA + (size_t)total;

    const int blocks = 8 * CB * B;   // rbg-major; block = 4 row-band waves

    // 41 ops (t=0..40): 5 passes of K=7, then K=6.
    pass_kernel<7,true, true ><<<blocks,256,0,stream>>>(img,  bufA, skel); // t=0..6
    pass_kernel<7,false,true ><<<blocks,256,0,stream>>>(bufA, bufB, skel); // t=7..13
    pass_kernel<7,false,true ><<<blocks,256,0,stream>>>(bufB, bufA, skel); // t=14..20
    pass_kernel<7,false,true ><<<blocks,256,0,stream>>>(bufA, bufB, skel); // t=21..27
    pass_kernel<7,false,true ><<<blocks,256,0,stream>>>(bufB, bufA, skel); // t=28..34
    pass_kernel<6,false,false><<<blocks,256,0,stream>>>(bufA, nullptr, skel); // t=35..40
}

// Round 11
// 263.961 us; speedup vs baseline: 1.4528x; 1.0026x over previous
//
#include <hip/hip_runtime.h>
#include <math.h>

#define WID 1024
#define HEI 1024
#define OUTC 48      // output cols per wave
#define HALOC 8      // halo lanes each side (supports K<=7)
#define BH 16        // output rows per wave
#define CB 22        // col bands: 21*48 + 16 = 1024
#define RB 64        // row bands: 8 XCD stripes * 8 bands

__device__ __forceinline__ float lane_up1(float v) {   // lane i <- lane i-1
    return __int_as_float(__builtin_amdgcn_update_dpp(
        __float_as_int(v), __float_as_int(v), 0x138, 0xF, 0xF, false)); // wave_shr:1
}
__device__ __forceinline__ float lane_dn1(float v) {   // lane i <- lane i+1
    return __int_as_float(__builtin_amdgcn_update_dpp(
        __float_as_int(v), __float_as_int(v), 0x130, 0xF, 0xF, false)); // wave_shl:1
}
__device__ __forceinline__ float fmin3(float a, float b, float c) {
    float d; asm("v_min3_f32 %0, %1, %2, %3" : "=v"(d) : "v"(a), "v"(b), "v"(c));
    return d;
}
__device__ __forceinline__ float fmax3(float a, float b, float c) {
    float d; asm("v_max3_f32 %0, %1, %2, %3" : "=v"(d) : "v"(a), "v"(b), "v"(c));
    return d;
}

// ---------------- fast body: interior waves, fully static sweep, depth-3 prefetch ----
template<int K, bool FIRST, bool WIMG>
__device__ __forceinline__ void fast_body(const float* __restrict__ imgp,
                                          float* __restrict__ outi,
                                          float* __restrict__ outs,
                                          int r0, int x, bool outLane)
{
    constexpr int NS = BH + 2*K + 2;
    const float INF = INFINITY;
    float wu[K+1], wc[K+1], wd[K+1], sk[K];
    #pragma unroll
    for (int j = 0; j <= K; ++j) { wu[j]=INF; wc[j]=INF; wd[j]=INF; }
    #pragma unroll
    for (int t = 0; t < K; ++t) sk[t] = 0.f;

    const int i0 = r0 - K - 1;
    const float* pI  = imgp + (size_t)(i0+3)*WID + x;  // img row for step s+3
    const float* pS  = outs + (size_t)(r0+3)*WID + x;  // skel row for step s+3
    float*       pSS = outs + (size_t)r0*WID + x;      // skel stores from s=2K+2
    float*       pSI = outi + (size_t)r0*WID + x;      // img stores from s=2K+1

    // depth-3 prefetch rings; slot = consuming step % 3 (static under full unroll)
    float vb[3], sb[3] = {0.f, 0.f, 0.f};
    #pragma unroll
    for (int i = 0; i < 3; ++i) vb[i] = imgp[(size_t)(i0+i)*WID + x];   // consumed s=0,1,2
    if (!FIRST) {
        #pragma unroll
        for (int i = 0; i < 3; ++i)                                     // consumed s=K+3+i
            sb[(K+3+i)%3] = outs[(size_t)(r0+i)*WID + x];
    }

    #pragma unroll
    for (int s = 0; s < NS; ++s) {
        float vcur = vb[s%3];
        if (s+3 <= NS-1) { vb[s%3] = pI[0]; pI += WID; }   // row for step s+3
        float scur = sb[s%3];
        if (!FIRST && (s+3 >= K+6) && (s+3 <= BH+K+2)) { sb[s%3] = pS[0]; pS += WID; }

        // stage 0 (img) shift
        wu[0] = wc[0]; wc[0] = wd[0]; wd[0] = vcur;

        // erode stages, triangle: stage j active from s = 2j
        #pragma unroll
        for (int j = 1; j <= K; ++j) {
            if (s >= 2*j) {
                float ce = wc[j-1];
                float lf = lane_up1(ce), rt = lane_dn1(ce);
                float pre = fmin3(wu[j-1], ce, lf);
                float nj  = fmin3(pre, rt, wd[j-1]);
                wu[j] = wc[j]; wc[j] = wd[j]; wd[j] = nj;
            }
        }

        // skel ring shift; fresh row enters
        #pragma unroll
        for (int t = K-1; t >= 1; --t) sk[t] = sk[t-1];
        sk[0] = FIRST ? 0.f : scur;

        // dilate+update ops, triangle: op t active s in [K+3+t, K+2+BH+t]
        #pragma unroll
        for (int t = 0; t < K; ++t) {
            if (s >= K+3+t && s <= K+2+BH+t) {
                float vm = fmax3(wu[t+1], wc[t+1], wd[t+1]);
                float hl = lane_up1(vm), hr = lane_dn1(vm);
                float d  = fmax3(hl, hr, vm);
                float delta = fmaxf(wu[t] - d, 0.f);
                float sv = sk[t];
                sk[t] = sv + fmaf(-sv, delta, delta);   // delta*(1-sv) >= 0
            }
        }

        if (s >= 2*K+2) { if (outLane) pSS[0] = sk[K-1]; pSS += WID; }
        if (WIMG) {
            if (s >= 2*K+1 && s <= BH+2*K) { if (outLane) pSI[0] = wd[K]; pSI += WID; }
        }
    }
}

// ---------------- masked body: boundary waves ----------------
template<int K, bool FIRST, bool WIMG>
__device__ __forceinline__ void masked_body(const float* __restrict__ imgp,
                                            float* __restrict__ outi,
                                            float* __restrict__ outs,
                                            int r0, int x, bool colIn, bool outLane)
{
    const float INF = INFINITY;
    float wu[K+1], wc[K+1], wd[K+1], sk[K];
    #pragma unroll
    for (int j = 0; j <= K; ++j) { wu[j]=INF; wc[j]=INF; wd[j]=INF; }
    #pragma unroll
    for (int t = 0; t < K; ++t) sk[t] = 0.f;

    const int i0 = r0 - K - 1;
    const int isteps = BH + 2*K + 2;

    float vcur = (colIn && (unsigned)i0 < (unsigned)HEI) ? imgp[(size_t)i0*WID + x] : INF;
    float scur = 0.f;
    if (!FIRST) {
        int sr = i0 - 2;
        if (colIn && sr >= r0 && sr < r0+BH) scur = outs[(size_t)sr*WID + x];
    }

    #pragma unroll 1
    for (int s = 0; s < isteps; ++s) {
        const int i = i0 + s;
        float vnext, snext = 0.f;
        {
            int rn = i + 1;
            vnext = (colIn && (unsigned)rn < (unsigned)HEI) ? imgp[(size_t)rn*WID + x] : INF;
        }
        if (!FIRST) {
            int sr = i - 1;
            if (colIn && sr >= r0 && sr < r0+BH) snext = outs[(size_t)sr*WID + x];
        }

        wu[0] = wc[0]; wc[0] = wd[0]; wd[0] = vcur;
        #pragma unroll
        for (int j = 1; j <= K; ++j) {
            float ce = wc[j-1];
            float lf = lane_up1(ce), rt = lane_dn1(ce);
            float pre = fmin3(wu[j-1], ce, lf);
            float nj  = fmin3(pre, rt, wd[j-1]);
            int rj = i - j;
            nj = ((unsigned)rj < (unsigned)HEI) ? nj : INF;
            nj = colIn ? nj : INF;
            wu[j] = wc[j]; wc[j] = wd[j]; wd[j] = nj;
        }
        #pragma unroll
        for (int t = K-1; t >= 1; --t) sk[t] = sk[t-1];
        sk[0] = FIRST ? 0.f : scur;
        #pragma unroll
        for (int t = 0; t < K; ++t) {
            int ro = i - 2 - t;
            float um = (ro >= 1)     ? wu[t+1] : -INF;
            float dm = (ro <= HEI-2) ? wd[t+1] : -INF;
            float vm = fmax3(um, dm, wc[t+1]);
            vm = colIn ? vm : -INF;
            float hl = lane_up1(vm), hr = lane_dn1(vm);
            float d  = fmax3(hl, hr, vm);
            float delta = fmaxf(wu[t] - d, 0.f);
            float sv = sk[t];
            sk[t] = sv + fmaf(-sv, delta, delta);
        }
        {
            int rs = i - K - 1;
            if (rs >= r0 && rs < r0+BH && outLane) outs[(size_t)rs*WID + x] = sk[K-1];
        }
        if (WIMG) {
            int re = i - K;
            if (re >= r0 && re < r0+BH && outLane) outi[(size_t)re*WID + x] = wd[K];
        }
        vcur = vnext; scur = snext;
    }
}

template<int K, bool FIRST, bool WIMG>
__global__ __launch_bounds__(256, 4)
void pass_kernel(const float* __restrict__ img_in, float* __restrict__ img_out,
                 float* __restrict__ skel)
{
    const int lane = threadIdx.x & 63;
    const int warp = threadIdx.x >> 6;
    // XCD swizzle: rbg = bid&7 -> XCD id (round-robin dispatch); each XCD owns a
    // contiguous 128-row stripe (8 bands); 2 blocks (sub) per stripe per col-band.
    const int bid   = blockIdx.x;
    const int rbg   = bid & 7;
    const int rest  = bid >> 3;
    const int sub   = rest & 1;
    const int rest2 = rest >> 1;
    const int cb    = rest2 % CB;
    const int b     = rest2 / CB;
    const int rb    = rbg*8 + sub*4 + warp;   // 0..63

    const int outc = (cb == CB-1) ? (WID - (CB-1)*OUTC) : OUTC;  // 48 or 16
    const int x0   = cb*OUTC - HALOC;
    const int r0   = rb*BH;
    const int x    = x0 + lane;
    const bool colIn   = ((unsigned)x < (unsigned)WID);
    const bool outLane = (lane >= HALOC) && (lane < HALOC + outc);
    const size_t base = (size_t)b*HEI*WID;

    const float* imgp = img_in + base;
    float* outi = WIMG ? (img_out + base) : nullptr;
    float* outs = skel + base;

    const bool fast = (cb >= 1) && (cb <= CB-2) && (rb >= 1) && (rb <= RB-2);
    if (fast)
        fast_body<K, FIRST, WIMG>(imgp, outi, outs, r0, x, outLane);
    else
        masked_body<K, FIRST, WIMG>(imgp, outi, outs, r0, x, colIn, outLane);
}

extern "C" void kernel_launch(void* const* d_in, const int* in_sizes, int n_in,
                              void* d_out, int out_size, void* d_ws, size_t ws_size,
                              hipStream_t stream)
{
    const float* img = (const float*)d_in[0];
    float* skel = (float*)d_out;
    const int total = in_sizes[0];
    const int B = total / (HEI*WID);

    float* bufA = (float*)d_ws;
    float* bufB = bufA + (size_t)total;

    const int blocks = 8 * 2 * CB * B;   // rbg-minor; block = 4 consecutive row-band waves

    // 41 ops (t=0..40): 5 passes of K=7, then K=6.
    pass_kernel<7,true, true ><<<blocks,256,0,stream>>>(img,  bufA, skel); // t=0..6
    pass_kernel<7,false,true ><<<blocks,256,0,stream>>>(bufA, bufB, skel); // t=7..13
    pass_kernel<7,false,true ><<<blocks,256,0,stream>>>(bufB, bufA, skel); // t=14..20
    pass_kernel<7,false,true ><<<blocks,256,0,stream>>>(bufA, bufB, skel); // t=21..27
    pass_kernel<7,false,true ><<<blocks,256,0,stream>>>(bufB, bufA, skel); // t=28..34
    pass_kernel<6,false,false><<<blocks,256,0,stream>>>(bufA, nullptr, skel); // t=35..40
}

// Round 12
// 167.534 us; speedup vs baseline: 2.2890x; 1.5756x over previous
//
#include <hip/hip_runtime.h>
#include <math.h>

#define WID 1024
#define HEI 1024
#define OUTC 48      // output cols per wave
#define HALOC 8      // halo lanes each side (supports K<=7)
#define BH 32        // output rows per wave
#define CB 22        // col bands: 21*48 + 16 = 1024
#define RB 32        // row bands: 8 XCD stripes * 4 warps

__device__ __forceinline__ float lane_up1(float v) {   // lane i <- lane i-1
    return __int_as_float(__builtin_amdgcn_update_dpp(
        __float_as_int(v), __float_as_int(v), 0x138, 0xF, 0xF, false)); // wave_shr:1
}
__device__ __forceinline__ float lane_dn1(float v) {   // lane i <- lane i+1
    return __int_as_float(__builtin_amdgcn_update_dpp(
        __float_as_int(v), __float_as_int(v), 0x130, 0xF, 0xF, false)); // wave_shl:1
}
__device__ __forceinline__ float fmin3(float a, float b, float c) {
    float d; asm("v_min3_f32 %0, %1, %2, %3" : "=v"(d) : "v"(a), "v"(b), "v"(c));
    return d;
}
__device__ __forceinline__ float fmax3(float a, float b, float c) {
    float d; asm("v_max3_f32 %0, %1, %2, %3" : "=v"(d) : "v"(a), "v"(b), "v"(c));
    return d;
}

// 4-rows-per-step fused pipeline. All row indices compile-time (full unroll).
// EDGE: runtime row/col masking (boundary waves). PLAIN: no masking (interior).
template<int K, bool FIRST, bool WIMG, bool EDGE>
__device__ __forceinline__ void body4(const float* __restrict__ imgp,
                                      float* __restrict__ outi,
                                      float* __restrict__ outs,
                                      int r0, int x, int xc, bool colIn, bool outLane)
{
    constexpr int FILL  = ((K & 3) == 3) ? (K + 6) : (K + 8);  // 13 (K=7), 14 (K=6)
    constexpr int NSTEP = (BH + 20) / 4;                        // 13
    const float INF = INFINITY;

    float c[K+1], d[K+1], sk[16];
    #pragma unroll
    for (int j = 0; j <= K; ++j) { c[j] = INF; d[j] = INF; }
    #pragma unroll
    for (int t = 0; t < 16; ++t) sk[t] = 0.f;

    float vI[4], vS[4] = {0.f, 0.f, 0.f, 0.f};

    // prime img loads: rows for step 1 (rr = 1-FILL+q)
    #pragma unroll
    for (int q = 0; q < 4; ++q) {
        const int rr = 1 - FILL + q;
        if (EDGE) {
            int row = r0 + rr;
            bool rin = (unsigned)row < (unsigned)HEI;
            int rowc = row < 0 ? 0 : (row > HEI-1 ? HEI-1 : row);
            float v = imgp[(size_t)rowc * WID + xc];
            vI[q] = (rin && colIn) ? v : INF;
        } else {
            vI[q] = imgp[(size_t)(r0 + rr) * WID + x];
        }
    }

    #pragma unroll
    for (int n = 1; n <= NSTEP; ++n) {
        // ---- stage-0 buffer: rows 4n-FILL-5 .. 4n-FILL (c,d,new0..3) ----
        float bp[6] = { c[0], d[0], vI[0], vI[1], vI[2], vI[3] };
        c[0] = bp[4]; d[0] = bp[5];

        // ---- entering skel rows (op-0 window this step) ----
        #pragma unroll
        for (int q = 0; q < 4; ++q) {
            const int rrE = 4*n - FILL - 5 + q;
            if (rrE >= 0 && rrE < BH) sk[rrE & 15] = FIRST ? 0.f : vS[q];
        }

        // ---- prefetch loads for step n+1 ----
        if (n < NSTEP) {
            #pragma unroll
            for (int q = 0; q < 4; ++q) {
                const int rr = 4*(n+1) - FILL - 3 + q;
                if (EDGE) {
                    int row = r0 + rr;
                    bool rin = (unsigned)row < (unsigned)HEI;
                    int rowc = row < 0 ? 0 : (row > HEI-1 ? HEI-1 : row);
                    float v = imgp[(size_t)rowc * WID + xc];
                    vI[q] = (rin && colIn) ? v : INF;
                } else {
                    vI[q] = imgp[(size_t)(r0 + rr) * WID + x];
                }
            }
            if (!FIRST) {
                #pragma unroll
                for (int q = 0; q < 4; ++q) {
                    const int rrL = 4*(n+1) - FILL - 5 + q;
                    if (rrL >= 0 && rrL < BH)
                        vS[q] = EDGE ? outs[(size_t)(r0 + rrL) * WID + xc]
                                     : outs[(size_t)(r0 + rrL) * WID + x];
                }
            }
        }

        float eK[6];

        // ---- stages j=1..K, each followed by op t=j-1 ----
        #pragma unroll
        for (int j = 1; j <= K; ++j) {
            float o[4];
            #pragma unroll
            for (int q = 0; q < 4; ++q) {
                float up = bp[q], ce = bp[q+1], dn = bp[q+2];
                float lf = lane_up1(ce), rt = lane_dn1(ce);
                float pre = fmin3(up, ce, lf);
                float nj  = fmin3(pre, rt, dn);
                if (EDGE) {
                    const int rr = 4*n - FILL - 3 - j + q;
                    bool rin = (unsigned)(r0 + rr) < (unsigned)HEI;
                    nj = (rin && colIn) ? nj : INF;
                }
                o[q] = nj;
            }
            float bc[6] = { c[j], d[j], o[0], o[1], o[2], o[3] };
            c[j] = bc[4]; d[j] = bc[5];

            // op t = j-1: output rows rr = 4n-FILL-5-t+q, e1 = bp[q], dilate over bc
            {
                const int t = j - 1;
                #pragma unroll
                for (int q = 0; q < 4; ++q) {
                    const int rr = 4*n - FILL - 5 - t + q;
                    float a0 = bc[q], a1 = bc[q+1], a2 = bc[q+2];
                    if (EDGE) {
                        bool i0 = (unsigned)(r0 + rr - 1) < (unsigned)HEI;
                        bool i1 = (unsigned)(r0 + rr    ) < (unsigned)HEI;
                        bool i2 = (unsigned)(r0 + rr + 1) < (unsigned)HEI;
                        a0 = i0 ? a0 : -INF;
                        a1 = i1 ? a1 : -INF;
                        a2 = i2 ? a2 : -INF;
                    }
                    float vm = fmax3(a0, a1, a2);
                    if (EDGE) vm = colIn ? vm : -INF;
                    float hl = lane_up1(vm), hr = lane_dn1(vm);
                    float dd = fmax3(hl, hr, vm);
                    float delta = fmaxf(bp[q] - dd, 0.f);
                    float sv = sk[rr & 15];
                    sk[rr & 15] = sv + fmaf(-sv, delta, delta);
                }
            }
            #pragma unroll
            for (int p = 0; p < 6; ++p) bp[p] = bc[p];
            if (j == K) {
                #pragma unroll
                for (int p = 0; p < 6; ++p) eK[p] = bc[p];
            }
        }

        // ---- stores: rows 4n-24+q (skel final after op K-1; E^K = eK[1+q]) ----
        #pragma unroll
        for (int q = 0; q < 4; ++q) {
            const int rr = 4*n - 24 + q;
            if (rr >= 0 && rr < BH) {
                if (outLane) outs[(size_t)(r0 + rr) * WID + x] = sk[rr & 15];
                if (WIMG) { if (outLane) outi[(size_t)(r0 + rr) * WID + x] = eK[1 + q]; }
            }
        }
    }
}

template<int K, bool FIRST, bool WIMG>
__global__ __launch_bounds__(256, 3)
void pass_kernel(const float* __restrict__ img_in, float* __restrict__ img_out,
                 float* __restrict__ skel)
{
    const int lane = threadIdx.x & 63;
    const int warp = threadIdx.x >> 6;
    // XCD swizzle: rbg = bid&7 -> XCD; each XCD owns a contiguous 128-row stripe.
    const int bid  = blockIdx.x;
    const int rbg  = bid & 7;
    const int rest = bid >> 3;
    const int cb   = rest % CB;
    const int b    = rest / CB;
    const int rb   = rbg*4 + warp;   // 0..31

    const int outc = (cb == CB-1) ? (WID - (CB-1)*OUTC) : OUTC;  // 48 or 16
    const int x0   = cb*OUTC - HALOC;
    const int r0   = rb*BH;
    const int x    = x0 + lane;
    const int xc   = x < 0 ? 0 : (x > WID-1 ? WID-1 : x);
    const bool colIn   = ((unsigned)x < (unsigned)WID);
    const bool outLane = (lane >= HALOC) && (lane < HALOC + outc);
    const size_t base = (size_t)b*HEI*WID;

    const float* imgp = img_in + base;
    float* outi = WIMG ? (img_out + base) : nullptr;
    float* outs = skel + base;

    const bool edge = (cb == 0) || (cb == CB-1) || (rb == 0) || (rb == RB-1);
    if (edge)
        body4<K, FIRST, WIMG, true >(imgp, outi, outs, r0, x, xc, colIn, outLane);
    else
        body4<K, FIRST, WIMG, false>(imgp, outi, outs, r0, x, xc, colIn, outLane);
}

extern "C" void kernel_launch(void* const* d_in, const int* in_sizes, int n_in,
                              void* d_out, int out_size, void* d_ws, size_t ws_size,
                              hipStream_t stream)
{
    const float* img = (const float*)d_in[0];
    float* skel = (float*)d_out;
    const int total = in_sizes[0];
    const int B = total / (HEI*WID);

    float* bufA = (float*)d_ws;
    float* bufB = bufA + (size_t)total;

    const int blocks = 8 * CB * B;   // 4 row-band waves per block

    // 41 ops (t=0..40): 5 passes of K=7, then K=6.
    pass_kernel<7,true, true ><<<blocks,256,0,stream>>>(img,  bufA, skel); // t=0..6
    pass_kernel<7,false,true ><<<blocks,256,0,stream>>>(bufA, bufB, skel); // t=7..13
    pass_kernel<7,false,true ><<<blocks,256,0,stream>>>(bufB, bufA, skel); // t=14..20
    pass_kernel<7,false,true ><<<blocks,256,0,stream>>>(bufA, bufB, skel); // t=21..27
    pass_kernel<7,false,true ><<<blocks,256,0,stream>>>(bufB, bufA, skel); // t=28..34
    pass_kernel<6,false,false><<<blocks,256,0,stream>>>(bufA, nullptr, skel); // t=35..40
}